// Round 3
// baseline (864.875 us; speedup 1.0000x reference)
//
#include <hip/hip_runtime.h>
#include <hip/hip_bf16.h>

typedef __attribute__((ext_vector_type(8))) short short8;
typedef __attribute__((ext_vector_type(4))) float float4v;

#define Hh 128
#define Ss 200
#define Ee 64
#define BR 16      // batch rows per block (GRU kernel)
#define TPB 512    // 8 waves
#define CH 8       // x prefetch chunk (steps)

#define LOG2E 1.442695040888963f

__device__ __forceinline__ float fexp2(float x) { return __builtin_amdgcn_exp2f(x); }
__device__ __forceinline__ float frcp(float x)  { return __builtin_amdgcn_rcpf(x); }

__device__ __forceinline__ float fsig(float z) {
    return frcp(1.0f + fexp2(-LOG2E * z));
}
__device__ __forceinline__ float ftanh(float z) {
    return 1.0f - 2.0f * frcp(1.0f + fexp2(2.0f * LOG2E * z));
}

// round-to-nearest-even float -> bf16 bits
__device__ __forceinline__ short f2bf(float f) {
    unsigned u = __float_as_uint(f);
    u += 0x7FFFu + ((u >> 16) & 1u);
    return (short)(u >> 16);
}
// pack 2 floats -> 2 bf16 in one u32 (low = a, high = b), RNE
__device__ __forceinline__ unsigned pk2(float a, float b) {
    __hip_bfloat162 t = __float22bfloat162_rn(make_float2(a, b));
    union { __hip_bfloat162 h; unsigned u; } c; c.h = t; return c.u;
}

// ---------------- Kernel 1: fused v = W_bil@e, logits, softmax -> att[B,S] ----------------
__global__ __launch_bounds__(256) void attn_kernel(
    const float* __restrict__ x, const float* __restrict__ tgt,
    const float* __restrict__ Wb, float* __restrict__ att)
{
    __shared__ float tgS[64];
    __shared__ float vS[128];
    __shared__ __align__(16) float tile[100][132];   // 100 rows/chunk, +4 pad (16B-aligned rows)
    __shared__ float lg[256];
    __shared__ float redM, redZ;

    int tid = threadIdx.x;
    int b = blockIdx.x;

    if (tid < 64) tgS[tid] = tgt[(size_t)b * Ee + tid];
    __syncthreads();

    if (tid < 128) {
        const float4v* wr = (const float4v*)(Wb + tid * Ee);
        float s = 0.f;
        #pragma unroll
        for (int e4 = 0; e4 < 16; ++e4) {
            float4v w = wr[e4];
            s += w.x * tgS[e4 * 4] + w.y * tgS[e4 * 4 + 1]
               + w.z * tgS[e4 * 4 + 2] + w.w * tgS[e4 * 4 + 3];
        }
        vS[tid] = s;
    }
    __syncthreads();

    #pragma unroll 1
    for (int c = 0; c < 2; ++c) {
        int r0 = c * 100;
        const float4v* src = (const float4v*)(x + ((size_t)b * Ss + r0) * Hh);
        for (int i = tid; i < 100 * 32; i += 256) {
            float4v f = src[i];
            *(float4v*)&tile[i >> 5][(i & 31) * 4] = f;
        }
        __syncthreads();
        if (tid < 100) {
            float s = 0.f;
            #pragma unroll 8
            for (int e4 = 0; e4 < 32; ++e4) {
                float4v t = *(const float4v*)&tile[tid][e4 * 4];
                s += t.x * vS[e4 * 4] + t.y * vS[e4 * 4 + 1]
                   + t.z * vS[e4 * 4 + 2] + t.w * vS[e4 * 4 + 3];
            }
            lg[r0 + tid] = s;
        }
        __syncthreads();
    }

    if (tid < 64) {
        float m = -1e30f;
        for (int s = tid; s < Ss; s += 64) m = fmaxf(m, lg[s]);
        #pragma unroll
        for (int off = 32; off > 0; off >>= 1) m = fmaxf(m, __shfl_xor(m, off));
        float z = 0.f;
        for (int s = tid; s < Ss; s += 64) z += fexp2((lg[s] - m) * LOG2E);
        #pragma unroll
        for (int off = 32; off > 0; off >>= 1) z += __shfl_xor(z, off);
        if (tid == 0) { redM = m; redZ = frcp(z); }
    }
    __syncthreads();

    if (tid < Ss)
        att[(size_t)b * Ss + tid] = fexp2((lg[tid] - redM) * LOG2E) * redZ;
}

// ---------------- Kernel 2: attention-gated GRU; u/r/c/h column-owned per wave ----------------
__global__ __launch_bounds__(TPB, 2) void gru_kernel(
    const float* __restrict__ x, const float* __restrict__ att,
    const float* __restrict__ Wxu, const float* __restrict__ Whu, const float* __restrict__ bu,
    const float* __restrict__ Wxr, const float* __restrict__ Whr, const float* __restrict__ br,
    const float* __restrict__ Wxc, const float* __restrict__ Whc, const float* __restrict__ bc,
    float* __restrict__ out)
{
    __shared__ __align__(16) short xh[BR][264];   // [x(0..127) | h(128..255)] bf16, +8 pad
    __shared__ __align__(16) short rhs[BR][136];  // r*h bf16, +8 pad
    __shared__ float attS[BR][Ss];

    int tid = threadIdx.x;
    int wave = tid >> 6, lane = tid & 63;
    int quad = lane >> 4, l16 = lane & 15;
    int odd = l16 & 1;
    int b0 = blockIdx.x * BR;
    int cw = wave * 16 + l16;      // this thread's owned column (0..127) for u,r,c,h

    // ---- one-time: weight B-fragments (col cw) in registers ----
    short8 Wu[8], Wr[8], Wcx[4], Wch[4];
    #pragma unroll
    for (int q = 0; q < 8; ++q) {
        short8 fu, fr;
        #pragma unroll
        for (int j = 0; j < 8; ++j) {
            int k = q * 32 + quad * 8 + j;        // 0..255 over [x|h]
            fu[j] = f2bf(k < 128 ? Wxu[k * Hh + cw] : Whu[(k - 128) * Hh + cw]);
            fr[j] = f2bf(k < 128 ? Wxr[k * Hh + cw] : Whr[(k - 128) * Hh + cw]);
        }
        Wu[q] = fu; Wr[q] = fr;
    }
    #pragma unroll
    for (int q = 0; q < 4; ++q) {
        short8 fx, fh;
        #pragma unroll
        for (int j = 0; j < 8; ++j) {
            int k = q * 32 + quad * 8 + j;        // 0..127
            fx[j] = f2bf(Wxc[k * Hh + cw]);
            fh[j] = f2bf(Whc[k * Hh + cw]);
        }
        Wcx[q] = fx; Wch[q] = fh;
    }
    float bU = bu[cw], bR = br[cw], bC = bc[cw];

    // ---- preload attention ----
    for (int i = tid; i < BR * Ss; i += TPB) {
        int rr = i / Ss, sc = i % Ss;
        attS[rr][sc] = att[(size_t)(b0 + rr) * Ss + sc];
    }

    // ---- x stager mapping ----
    int urow = tid >> 5, uc = (tid & 31) * 4;
    const float* xrow = x + (size_t)(b0 + urow) * Ss * Hh + uc;

    float hm[4] = {0.f, 0.f, 0.f, 0.f};   // h master: rows quad*4+r, col cw (fp32)
    float4v xch[CH];

    // preamble: h0 = 0, stage x0
    { uint2 z; z.x = 0; z.y = 0; *(uint2*)&xh[urow][128 + uc] = z; }
    {
        float4v xv = *(const float4v*)xrow;
        uint2 w; w.x = pk2(xv[0], xv[1]); w.y = pk2(xv[2], xv[3]);
        *(uint2*)&xh[urow][uc] = w;
    }

    #pragma unroll 1
    for (int t = 0; t < Ss; ++t) {
        __syncthreads();   // B_h: x_t + h_t visible

        // phase 1: u, r (K=256 over [x|h]) and x-part of c (K=128)
        float4v aU = {bU, bU, bU, bU};
        float4v aR = {bR, bR, bR, bR};
        float4v aC = {bC, bC, bC, bC};
        #pragma unroll
        for (int q = 0; q < 8; ++q) {
            short8 af = *(const short8*)&xh[l16][q * 32 + quad * 8];
            aU = __builtin_amdgcn_mfma_f32_16x16x32_bf16(af, Wu[q], aU, 0, 0, 0);
            aR = __builtin_amdgcn_mfma_f32_16x16x32_bf16(af, Wr[q], aR, 0, 0, 0);
            if (q < 4)
                aC = __builtin_amdgcn_mfma_f32_16x16x32_bf16(af, Wcx[q], aC, 0, 0, 0);
        }
        float u[4], rh[4];
        #pragma unroll
        for (int r = 0; r < 4; ++r) {
            u[r] = fsig(aU[r]);
            rh[r] = fsig(aR[r]) * hm[r];   // r*h from fp32 master
        }
        // pack r*h (bf16) -> rhs: exchange with col-partner lane, 2x b32 writes
        {
            unsigned s01 = pk2(rh[0], rh[1]), s23 = pk2(rh[2], rh[3]);
            unsigned send = odd ? s01 : s23;
            unsigned recv = (unsigned)__shfl_xor((int)send, 1);
            unsigned A = odd ? recv : s01;
            unsigned Bv = odd ? s23 : recv;
            int r0 = quad * 4 + (odd ? 2 : 0);
            int colp = cw & ~1;
            *(unsigned*)&rhs[r0][colp]     = (A & 0xffffu) | (Bv << 16);
            *(unsigned*)&rhs[r0 + 1][colp] = (A >> 16) | (Bv & 0xffff0000u);
        }
        __syncthreads();   // B_rhs

        // chunked x prefetch: issue right after barrier -> drains with ~phase2 elapsed
        if ((t & (CH - 1)) == 0) {
            #pragma unroll
            for (int k = 0; k < CH; ++k) {
                int tt = t + 1 + k; if (tt > Ss - 1) tt = Ss - 1;
                xch[k] = *(const float4v*)&xrow[(size_t)tt * Hh];
            }
        }

        // phase 2: c += (r*h) @ Whc
        #pragma unroll
        for (int q = 0; q < 4; ++q) {
            short8 af = *(const short8*)&rhs[l16][q * 32 + quad * 8];
            aC = __builtin_amdgcn_mfma_f32_16x16x32_bf16(af, Wch[q], aC, 0, 0, 0);
        }
        float a_[4];
        #pragma unroll
        for (int r = 0; r < 4; ++r) a_[r] = attS[quad * 4 + r][t];

        // update h in registers
        #pragma unroll
        for (int r = 0; r < 4; ++r) {
            float c = ftanh(aC[r]);
            float au = a_[r] * u[r];
            hm[r] += au * (c - hm[r]);
        }
        // pack h' (bf16) -> xh h-region
        {
            unsigned s01 = pk2(hm[0], hm[1]), s23 = pk2(hm[2], hm[3]);
            unsigned send = odd ? s01 : s23;
            unsigned recv = (unsigned)__shfl_xor((int)send, 1);
            unsigned A = odd ? recv : s01;
            unsigned Bv = odd ? s23 : recv;
            int r0 = quad * 4 + (odd ? 2 : 0);
            int colp = 128 + (cw & ~1);
            *(unsigned*)&xh[r0][colp]     = (A & 0xffffu) | (Bv << 16);
            *(unsigned*)&xh[r0 + 1][colp] = (A >> 16) | (Bv & 0xffff0000u);
        }
        // stage x_{t+1}
        if (t + 1 < Ss) {
            float4v xv = xch[t & (CH - 1)];
            uint2 w; w.x = pk2(xv[0], xv[1]); w.y = pk2(xv[2], xv[3]);
            *(uint2*)&xh[urow][uc] = w;
        }
    }

    // final h -> out[B,H]
    #pragma unroll
    for (int r = 0; r < 4; ++r)
        out[(size_t)(b0 + quad * 4 + r) * Hh + cw] = hm[r];
}

extern "C" void kernel_launch(void* const* d_in, const int* in_sizes, int n_in,
                              void* d_out, int out_size, void* d_ws, size_t ws_size,
                              hipStream_t stream) {
    const float* x   = (const float*)d_in[0];   // [B,S,H]
    const float* tgt = (const float*)d_in[1];   // [B,E]
    const float* Wb  = (const float*)d_in[2];   // [H,E]
    const float* Wxu = (const float*)d_in[3];
    const float* Whu = (const float*)d_in[4];
    const float* bu  = (const float*)d_in[5];
    const float* Wxr = (const float*)d_in[6];
    const float* Whr = (const float*)d_in[7];
    const float* br  = (const float*)d_in[8];
    const float* Wxc = (const float*)d_in[9];
    const float* Whc = (const float*)d_in[10];
    const float* bc  = (const float*)d_in[11];
    float* out = (float*)d_out;

    const int B = in_sizes[1] / Ee;             // 4096
    float* att = (float*)d_ws;                  // [B,S] fp32

    attn_kernel<<<B, 256, 0, stream>>>(x, tgt, Wb, att);
    gru_kernel<<<B / BR, TPB, 0, stream>>>(x, att, Wxu, Whu, bu,
                                           Wxr, Whr, br, Wxc, Whc, bc, out);
}